// Round 2
// baseline (459.815 us; speedup 1.0000x reference)
//
#include <hip/hip_runtime.h>
#include <stdint.h>

#define M_DIM 8192
#define K_DIM 4096
#define N_DIM 4096
#define FP8_MAX 448.0f
#define KT (K_DIM / 64)   // 64 k-tiles of depth 64

typedef float floatx16 __attribute__((ext_vector_type(16)));
typedef int intx8 __attribute__((ext_vector_type(8)));

// Tiled fp8 layout (unchanged, proven):
//   tensor -> [128-row x 64-k] tiles of 8192 B; tile (i=row/128, b=k/64) at
//   (i*(K/64)+b)*8192. Within a tile: row = mi*32 + r5, k = h*32 + kq*16 + j
//     offset = kq*4096 + mi*1024 + (h*32 + r5)*16
//   MFMA 32x32x64 fragment read = TWO ds_read_b128 at
//   (kq*4096 + mi*1024) + 16*lane  (lane-contiguous, conflict-free).
//
// GEMM v4: 256x256 tile, 8 waves (2Mx4N), 3-slot LDS (96 KB), prefetch
// distance 2. ONE barrier + ONE counted vmcnt(4) per K-tile, both at the
// top (waited loads were issued a full iteration earlier -> ~free).
// All 12 ds_reads issued in a staircase order so the compiler emits
// counted lgkmcnt(8/6/4/2/0) interleaved with the 8 MFMAs -> LDS drain
// overlaps the MFMA cluster within each wave (no phase lockstep).
// Correctness:
//  - reads of slot t%3 happen after [own vmcnt(4) -> barrier] => all waves'
//    stage loads for tile t are complete.
//  - gloads for t+2 (slot (t+2)%3, which held tile t-1) are issued after the
//    barrier; every wave's tile t-1 reads completed before its last MFMA of
//    iter t-1 (compiler lgkm dependency) => before it reached this barrier.

// ---------- helpers ----------

__device__ __forceinline__ uint32_t pack4_fp8(float a, float b, float c, float d) {
    int v = __builtin_amdgcn_cvt_pk_fp8_f32(a, b, 0, false);
    v = __builtin_amdgcn_cvt_pk_fp8_f32(c, d, v, true);
    return (uint32_t)v;
}

__device__ __forceinline__ void gload_lds16(const uint8_t* g, uint8_t* l) {
    __builtin_amdgcn_global_load_lds(
        (const __attribute__((address_space(1))) uint32_t*)g,
        (__attribute__((address_space(3))) uint32_t*)l,
        16, 0, 0);
}

__device__ __forceinline__ float scale_from_amax(float amax) {
    return FP8_MAX / fmaxf(amax, 1e-12f);
}

// ---------- kernel 0: init amax slots ----------

__global__ void init_amax_kernel(uint32_t* amax) {
    amax[0] = 0u;
    amax[1] = 0u;
}

// ---------- kernel 1: fused per-tensor amax (x and w in one launch) ----------

__global__ __launch_bounds__(256)
void amax_kernel(const float* __restrict__ x, const float* __restrict__ w,
                 uint32_t* __restrict__ out_bits) {
    bool isX = blockIdx.x < 2048;
    const float* src = isX ? x : w;
    long n4 = (isX ? (long)M_DIM * K_DIM : (long)K_DIM * N_DIM) >> 2;
    int bid = isX ? blockIdx.x : blockIdx.x - 2048;
    int nb = isX ? 2048 : 1024;
    long i = (long)bid * blockDim.x + threadIdx.x;
    long stride = (long)nb * blockDim.x;
    const float4* s4 = (const float4*)src;
    float m = 0.0f;
    for (long j = i; j < n4; j += stride) {
        float4 v = s4[j];
        m = fmaxf(m, fmaxf(fmaxf(fabsf(v.x), fabsf(v.y)), fmaxf(fabsf(v.z), fabsf(v.w))));
    }
    #pragma unroll
    for (int off = 32; off > 0; off >>= 1)
        m = fmaxf(m, __shfl_down(m, off, 64));
    __shared__ float smax[4];
    int wave = threadIdx.x >> 6;
    if ((threadIdx.x & 63) == 0) smax[wave] = m;
    __syncthreads();
    if (threadIdx.x == 0) {
        float bm = fmaxf(fmaxf(smax[0], smax[1]), fmaxf(smax[2], smax[3]));
        atomicMax(out_bits + (isX ? 0 : 1), __float_as_uint(bm));
    }
}

// ---------- kernel 2: fused quantize x and w -> tiled fp8 layouts ----------

__global__ __launch_bounds__(256)
void quant_kernel(const float* __restrict__ x, const float* __restrict__ w,
                  uint8_t* __restrict__ qx, uint8_t* __restrict__ qwT,
                  const uint32_t* __restrict__ amax_bits) {
    int b = blockIdx.x;
    if (b < 4096) {
        float scale = scale_from_amax(__uint_as_float(amax_bits[0]));
        int iy = b >> 6, ib = b & 63;
        const float* src = x + (long)iy * 128 * K_DIM;
        uint8_t* outT = qx + (size_t)b * 8192;
        int kb = ib * 64;
        #pragma unroll
        for (int it = 0; it < 2; ++it) {
            int G = threadIdx.x + it * 256;
            int kq = G >> 8, rem = G & 255;
            int mi = rem >> 6, h = (rem >> 5) & 1, r5 = rem & 31;
            const float4* p = (const float4*)(src + (long)(mi * 32 + r5) * K_DIM
                                              + kb + h * 32 + kq * 16);
            float4 v0 = p[0], v1 = p[1], v2 = p[2], v3 = p[3];
            uint4 o;
            o.x = pack4_fp8(v0.x * scale, v0.y * scale, v0.z * scale, v0.w * scale);
            o.y = pack4_fp8(v1.x * scale, v1.y * scale, v1.z * scale, v1.w * scale);
            o.z = pack4_fp8(v2.x * scale, v2.y * scale, v2.z * scale, v2.w * scale);
            o.w = pack4_fp8(v3.x * scale, v3.y * scale, v3.z * scale, v3.w * scale);
            *(uint4*)(outT + (size_t)G * 16) = o;   // consecutive G -> coalesced
        }
    } else {
        float scale = scale_from_amax(__uint_as_float(amax_bits[1]));
        b -= 4096;
        int iy = b >> 6, ib = b & 63;     // iy = n-tile
        int n0 = iy * 128, kb = ib * 64;
        uint8_t* outT = qwT + (size_t)b * 8192;
        #pragma unroll
        for (int it = 0; it < 2; ++it) {
            int G = threadIdx.x + it * 256;
            int kq = G >> 8, rem = G & 255;
            int mi = rem >> 6, h = (rem >> 5) & 1, r5 = rem & 31;
            int n = n0 + mi * 32 + r5;
            const float* col = w + (long)(kb + h * 32 + kq * 16) * N_DIM + n;
            float v[16];
            #pragma unroll
            for (int j = 0; j < 16; ++j)
                v[j] = col[(long)j * N_DIM] * scale;   // wave-coalesced per j
            uint4 o;
            o.x = pack4_fp8(v[0], v[1], v[2], v[3]);
            o.y = pack4_fp8(v[4], v[5], v[6], v[7]);
            o.z = pack4_fp8(v[8], v[9], v[10], v[11]);
            o.w = pack4_fp8(v[12], v[13], v[14], v[15]);
            *(uint4*)(outT + (size_t)G * 16) = o;
        }
    }
}

// ---------- kernel 3: MX-scaled fp8 MFMA GEMM, counted-wait pipeline ----------

#define UNIT_SCALE 0x7F7F7F7F   // e8m0 0x7F = 2^0 = 1.0 per 32-elem block

union Frag { intx8 v; int4 q[2]; };

#define MFMA_SC(A, B, Cacc) \
    __builtin_amdgcn_mfma_scale_f32_32x32x64_f8f6f4( \
        (A).v, (B).v, (Cacc), 0, 0, 0, UNIT_SCALE, 0, UNIT_SCALE)

__global__ __launch_bounds__(512, 2)
void gemm_kernel(const uint8_t* __restrict__ qx, const uint8_t* __restrict__ qwT,
                 const float* __restrict__ bias, float* __restrict__ C,
                 const uint32_t* __restrict__ amax_bits) {
    float sx = scale_from_amax(__uint_as_float(amax_bits[0]));
    float sw = scale_from_amax(__uint_as_float(amax_bits[1]));
    float dq = 1.0f / (sx * sw);

    // 3 slots x (A: 2x8KB chunks, B: 2x8KB chunks) = 96 KB
    __shared__ __align__(16) uint8_t lds[3 * 32768];

    int tid = threadIdx.x;
    int wave = tid >> 6;
    int lane = tid & 63;
    int wm = wave >> 2;        // 0..1 : 128 rows each
    int wn = wave & 3;         // 0..3 : 64 cols each
    int i0 = blockIdx.y * 2;   // first 128-row A tile index
    int j0 = blockIdx.x * 2;   // first 128-col B tile index

    const uint8_t* aSrc0 = qx  + ((size_t)(i0 + 0) * KT) * 8192 + tid * 16;
    const uint8_t* aSrc1 = qx  + ((size_t)(i0 + 1) * KT) * 8192 + tid * 16;
    const uint8_t* bSrc0 = qwT + ((size_t)(j0 + 0) * KT) * 8192 + tid * 16;
    const uint8_t* bSrc1 = qwT + ((size_t)(j0 + 1) * KT) * 8192 + tid * 16;

    // prologue: stage tile 0 -> slot0, tile 1 -> slot1 (8 gloads/thread)
    #pragma unroll
    for (int tt = 0; tt < 2; ++tt) {
        uint8_t* sl = lds + tt * 32768;
        size_t off = (size_t)tt * 8192;
        gload_lds16(aSrc0 + off, sl + tid * 16);
        gload_lds16(aSrc1 + off, sl + 8192 + tid * 16);
        gload_lds16(bSrc0 + off, sl + 16384 + tid * 16);
        gload_lds16(bSrc1 + off, sl + 24576 + tid * 16);
    }

    floatx16 acc[4][2];
    #pragma unroll
    for (int i = 0; i < 4; ++i)
        #pragma unroll
        for (int j = 0; j < 2; ++j)
            acc[i][j] = (floatx16)0.0f;

    int l16 = lane * 16;
    int s = 0;
    for (int t = 0; t < KT; ++t) {
        // wait own stage loads for tile t (keep tile t+1's 4 in flight),
        // then barrier => ALL waves' loads for tile t have landed.
        if (t == KT - 1) {
            asm volatile("s_waitcnt vmcnt(0)" ::: "memory");
        } else {
            asm volatile("s_waitcnt vmcnt(4)" ::: "memory");
        }
        __builtin_amdgcn_s_barrier();

        const uint8_t* slot = lds + s * 32768;
        const uint8_t* aB = slot + wm * 8192;                                  // wave's A chunk
        const uint8_t* bB = slot + 16384 + (wn >> 1) * 8192 + (wn & 1) * 2048; // wave's B half-chunk

        // --- fragment reads, staircase order (oldest reads feed first MFMAs) ---
        Frag fa0, fa1, fa2, fa3, fb0, fb1;
        fa0.q[0] = *(const int4*)(aB + l16);
        fa0.q[1] = *(const int4*)(aB + 4096 + l16);
        fb0.q[0] = *(const int4*)(bB + l16);
        fb0.q[1] = *(const int4*)(bB + 4096 + l16);
        fb1.q[0] = *(const int4*)(bB + 1024 + l16);
        fb1.q[1] = *(const int4*)(bB + 5120 + l16);
        fa1.q[0] = *(const int4*)(aB + 1024 + l16);
        fa1.q[1] = *(const int4*)(aB + 5120 + l16);

        // --- prefetch tile t+2 into the slot tile t-1 occupied ---
        int ns = s + 2; if (ns >= 3) ns -= 3;
        if (t + 2 < KT) {
            uint8_t* psl = lds + ns * 32768;
            size_t poff = (size_t)(t + 2) * 8192;
            gload_lds16(aSrc0 + poff, psl + tid * 16);
            gload_lds16(aSrc1 + poff, psl + 8192 + tid * 16);
            gload_lds16(bSrc0 + poff, psl + 16384 + tid * 16);
            gload_lds16(bSrc1 + poff, psl + 24576 + tid * 16);
        }

        // --- late reads (keep frag register peak low) ---
        fa2.q[0] = *(const int4*)(aB + 2048 + l16);
        fa2.q[1] = *(const int4*)(aB + 6144 + l16);
        fa3.q[0] = *(const int4*)(aB + 3072 + l16);
        fa3.q[1] = *(const int4*)(aB + 7168 + l16);

        // --- MFMA staircase: compiler emits counted lgkmcnt per dependency ---
        __builtin_amdgcn_s_setprio(1);
        acc[0][0] = MFMA_SC(fa0, fb0, acc[0][0]);
        acc[0][1] = MFMA_SC(fa0, fb1, acc[0][1]);
        acc[1][0] = MFMA_SC(fa1, fb0, acc[1][0]);
        acc[1][1] = MFMA_SC(fa1, fb1, acc[1][1]);
        acc[2][0] = MFMA_SC(fa2, fb0, acc[2][0]);
        acc[2][1] = MFMA_SC(fa2, fb1, acc[2][1]);
        acc[3][0] = MFMA_SC(fa3, fb0, acc[3][0]);
        acc[3][1] = MFMA_SC(fa3, fb1, acc[3][1]);
        __builtin_amdgcn_s_setprio(0);

        s = (s == 2) ? 0 : s + 1;
    }

    // epilogue: 32x32 C/D layout: col = lane&31, row = (reg&3) + 8*(reg>>2) + 4*(lane>>5)
    int cn = lane & 31;
    int h4 = (lane >> 5) * 4;
    long tileM = (long)blockIdx.y * 256;
    long tileN = (long)blockIdx.x * 256;
    #pragma unroll
    for (int ni = 0; ni < 2; ++ni) {
        long col = tileN + wn * 64 + ni * 32 + cn;
        float bv = bias[col];
        #pragma unroll
        for (int mi = 0; mi < 4; ++mi) {
            long rowBase = tileM + wm * 128 + mi * 32 + h4;
            floatx16 a = acc[mi][ni];
            #pragma unroll
            for (int rg = 0; rg < 4; ++rg) {
                long row = rowBase + 8 * rg;
                #pragma unroll
                for (int rr = 0; rr < 4; ++rr)
                    C[(row + rr) * N_DIM + col] = a[rg * 4 + rr] * dq + bv;
            }
        }
    }
}

// ---------- launch ----------

extern "C" void kernel_launch(void* const* d_in, const int* in_sizes, int n_in,
                              void* d_out, int out_size, void* d_ws, size_t ws_size,
                              hipStream_t stream) {
    const float* x = (const float*)d_in[0];     // [M][K]
    const float* w = (const float*)d_in[1];     // [K][N]
    const float* bias = (const float*)d_in[2];  // [N]
    float* out = (float*)d_out;                 // [M][N]

    uint32_t* amax = (uint32_t*)d_ws;           // [0]=amax_x, [1]=amax_w
    uint8_t* qx = (uint8_t*)d_ws + 256;
    uint8_t* qwT = qx + (size_t)M_DIM * K_DIM;

    init_amax_kernel<<<1, 64, 0, stream>>>(amax);
    amax_kernel<<<3072, 256, 0, stream>>>(x, w, amax);
    quant_kernel<<<6144, 256, 0, stream>>>(x, w, qx, qwT, amax);
    gemm_kernel<<<dim3(N_DIM / 256, M_DIM / 256), 512, 0, stream>>>(qx, qwT, bias, out, amax);
}

// Round 3
// 415.917 us; speedup vs baseline: 1.1055x; 1.1055x over previous
//
#include <hip/hip_runtime.h>
#include <stdint.h>

#define M_DIM 8192
#define K_DIM 4096
#define N_DIM 4096
#define FP8_MAX 448.0f
#define KT (K_DIM / 64)   // 64 k-tiles of depth 64

typedef float floatx16 __attribute__((ext_vector_type(16)));
typedef int intx8 __attribute__((ext_vector_type(8)));
typedef int intx4 __attribute__((ext_vector_type(4)));

// Tiled fp8 layout (unchanged, proven):
//   tensor -> [128-row x 64-k] tiles of 8192 B; tile (i=row/128, b=k/64) at
//   (i*(K/64)+b)*8192. Within a tile: row = mi*32 + r5, k = h*32 + kq*16 + j
//     offset = kq*4096 + mi*1024 + (h*32 + r5)*16
//   MFMA 32x32x64 fragment read = TWO ds_read_b128 at
//   (kq*4096 + mi*1024) + 16*lane  (lane-contiguous, conflict-free).
//
// GEMM v5 (vs v4):
//  - fragment loads are SSA intx4 pairs concatenated via shufflevector
//    (v4's union forced ~48 v_mov/iter of operand re-assembly on the
//    ds_read->MFMA critical path; VALUBusy 11% implicated)
//  - bijective XCD swizzle: 512 blocks -> 8 XCDs x 64-block (8Nx8M) regions;
//    blocks sharing A/B panels co-locate on one L2 (staging was running at
//    the 6.3 TB/s memory-path ceiling with 3x HBM re-fetch)
//  - setprio removed (m190: negative on lockstep GEMM)
// Sync structure (1 barrier + counted vmcnt(4)/iter, 3-slot LDS, prefetch
// distance 2) unchanged from the passing v4.

// ---------- helpers ----------

__device__ __forceinline__ uint32_t pack4_fp8(float a, float b, float c, float d) {
    int v = __builtin_amdgcn_cvt_pk_fp8_f32(a, b, 0, false);
    v = __builtin_amdgcn_cvt_pk_fp8_f32(c, d, v, true);
    return (uint32_t)v;
}

__device__ __forceinline__ void gload_lds16(const uint8_t* g, uint8_t* l) {
    __builtin_amdgcn_global_load_lds(
        (const __attribute__((address_space(1))) uint32_t*)g,
        (__attribute__((address_space(3))) uint32_t*)l,
        16, 0, 0);
}

__device__ __forceinline__ float scale_from_amax(float amax) {
    return FP8_MAX / fmaxf(amax, 1e-12f);
}

// fragment load: two ds_read_b128 at +0 / +4096, SSA concat (no union, no movs)
__device__ __forceinline__ intx8 frag_ld(const uint8_t* p) {
    intx4 lo = *(const intx4*)p;
    intx4 hi = *(const intx4*)(p + 4096);
    return __builtin_shufflevector(lo, hi, 0, 1, 2, 3, 4, 5, 6, 7);
}

// ---------- kernel 0: init amax slots ----------

__global__ void init_amax_kernel(uint32_t* amax) {
    amax[0] = 0u;
    amax[1] = 0u;
}

// ---------- kernel 1: fused per-tensor amax (x and w in one launch) ----------

__global__ __launch_bounds__(256)
void amax_kernel(const float* __restrict__ x, const float* __restrict__ w,
                 uint32_t* __restrict__ out_bits) {
    bool isX = blockIdx.x < 2048;
    const float* src = isX ? x : w;
    long n4 = (isX ? (long)M_DIM * K_DIM : (long)K_DIM * N_DIM) >> 2;
    int bid = isX ? blockIdx.x : blockIdx.x - 2048;
    int nb = isX ? 2048 : 1024;
    long i = (long)bid * blockDim.x + threadIdx.x;
    long stride = (long)nb * blockDim.x;
    const float4* s4 = (const float4*)src;
    float m = 0.0f;
    for (long j = i; j < n4; j += stride) {
        float4 v = s4[j];
        m = fmaxf(m, fmaxf(fmaxf(fabsf(v.x), fabsf(v.y)), fmaxf(fabsf(v.z), fabsf(v.w))));
    }
    #pragma unroll
    for (int off = 32; off > 0; off >>= 1)
        m = fmaxf(m, __shfl_down(m, off, 64));
    __shared__ float smax[4];
    int wave = threadIdx.x >> 6;
    if ((threadIdx.x & 63) == 0) smax[wave] = m;
    __syncthreads();
    if (threadIdx.x == 0) {
        float bm = fmaxf(fmaxf(smax[0], smax[1]), fmaxf(smax[2], smax[3]));
        atomicMax(out_bits + (isX ? 0 : 1), __float_as_uint(bm));
    }
}

// ---------- kernel 2: fused quantize x and w -> tiled fp8 layouts ----------

__global__ __launch_bounds__(256)
void quant_kernel(const float* __restrict__ x, const float* __restrict__ w,
                  uint8_t* __restrict__ qx, uint8_t* __restrict__ qwT,
                  const uint32_t* __restrict__ amax_bits) {
    int b = blockIdx.x;
    if (b < 4096) {
        float scale = scale_from_amax(__uint_as_float(amax_bits[0]));
        int iy = b >> 6, ib = b & 63;
        const float* src = x + (long)iy * 128 * K_DIM;
        uint8_t* outT = qx + (size_t)b * 8192;
        int kb = ib * 64;
        #pragma unroll
        for (int it = 0; it < 2; ++it) {
            int G = threadIdx.x + it * 256;
            int kq = G >> 8, rem = G & 255;
            int mi = rem >> 6, h = (rem >> 5) & 1, r5 = rem & 31;
            const float4* p = (const float4*)(src + (long)(mi * 32 + r5) * K_DIM
                                              + kb + h * 32 + kq * 16);
            float4 v0 = p[0], v1 = p[1], v2 = p[2], v3 = p[3];
            uint4 o;
            o.x = pack4_fp8(v0.x * scale, v0.y * scale, v0.z * scale, v0.w * scale);
            o.y = pack4_fp8(v1.x * scale, v1.y * scale, v1.z * scale, v1.w * scale);
            o.z = pack4_fp8(v2.x * scale, v2.y * scale, v2.z * scale, v2.w * scale);
            o.w = pack4_fp8(v3.x * scale, v3.y * scale, v3.z * scale, v3.w * scale);
            *(uint4*)(outT + (size_t)G * 16) = o;   // consecutive G -> coalesced
        }
    } else {
        float scale = scale_from_amax(__uint_as_float(amax_bits[1]));
        b -= 4096;
        int iy = b >> 6, ib = b & 63;     // iy = n-tile
        int n0 = iy * 128, kb = ib * 64;
        uint8_t* outT = qwT + (size_t)b * 8192;
        #pragma unroll
        for (int it = 0; it < 2; ++it) {
            int G = threadIdx.x + it * 256;
            int kq = G >> 8, rem = G & 255;
            int mi = rem >> 6, h = (rem >> 5) & 1, r5 = rem & 31;
            int n = n0 + mi * 32 + r5;
            const float* col = w + (long)(kb + h * 32 + kq * 16) * N_DIM + n;
            float v[16];
            #pragma unroll
            for (int j = 0; j < 16; ++j)
                v[j] = col[(long)j * N_DIM] * scale;   // wave-coalesced per j
            uint4 o;
            o.x = pack4_fp8(v[0], v[1], v[2], v[3]);
            o.y = pack4_fp8(v[4], v[5], v[6], v[7]);
            o.z = pack4_fp8(v[8], v[9], v[10], v[11]);
            o.w = pack4_fp8(v[12], v[13], v[14], v[15]);
            *(uint4*)(outT + (size_t)G * 16) = o;
        }
    }
}

// ---------- kernel 3: MX-scaled fp8 MFMA GEMM, counted-wait pipeline ----------

#define UNIT_SCALE 0x7F7F7F7F   // e8m0 0x7F = 2^0 = 1.0 per 32-elem block

#define MFMA_SC(A, B, Cacc) \
    __builtin_amdgcn_mfma_scale_f32_32x32x64_f8f6f4( \
        (A), (B), (Cacc), 0, 0, 0, UNIT_SCALE, 0, UNIT_SCALE)

__global__ __launch_bounds__(512, 2)
void gemm_kernel(const uint8_t* __restrict__ qx, const uint8_t* __restrict__ qwT,
                 const float* __restrict__ bias, float* __restrict__ C,
                 const uint32_t* __restrict__ amax_bits) {
    float sx = scale_from_amax(__uint_as_float(amax_bits[0]));
    float sw = scale_from_amax(__uint_as_float(amax_bits[1]));
    float dq = 1.0f / (sx * sw);

    // 3 slots x (A: 2x8KB chunks, B: 2x8KB chunks) = 96 KB
    __shared__ __align__(16) uint8_t lds[3 * 32768];

    int tid = threadIdx.x;
    int wave = tid >> 6;
    int lane = tid & 63;
    int wm = wave >> 2;        // 0..1 : 128 rows each
    int wn = wave & 3;         // 0..3 : 64 cols each

    // ---- bijective XCD swizzle: 512 blocks -> 8 regions of 8N x 8M tiles ----
    // dispatch linear id (x-major); xcd = id%8 (round-robin placement);
    // region per XCD: rx=xcd&1 (N half), ry=xcd>>1 (M quarter).
    int flat = blockIdx.y * gridDim.x + blockIdx.x;
    int xcd = flat & 7;
    int idx = flat >> 3;                  // 0..63 within region
    int bx = (xcd & 1) * 8 + (idx & 7);   // N-tile 0..15
    int by = (xcd >> 1) * 8 + (idx >> 3); // M-tile 0..31

    int i0 = by * 2;   // first 128-row A tile index
    int j0 = bx * 2;   // first 128-col B tile index

    const uint8_t* aSrc0 = qx  + ((size_t)(i0 + 0) * KT) * 8192 + tid * 16;
    const uint8_t* aSrc1 = qx  + ((size_t)(i0 + 1) * KT) * 8192 + tid * 16;
    const uint8_t* bSrc0 = qwT + ((size_t)(j0 + 0) * KT) * 8192 + tid * 16;
    const uint8_t* bSrc1 = qwT + ((size_t)(j0 + 1) * KT) * 8192 + tid * 16;

    // prologue: stage tile 0 -> slot0, tile 1 -> slot1 (8 gloads/thread)
    #pragma unroll
    for (int tt = 0; tt < 2; ++tt) {
        uint8_t* sl = lds + tt * 32768;
        size_t off = (size_t)tt * 8192;
        gload_lds16(aSrc0 + off, sl + tid * 16);
        gload_lds16(aSrc1 + off, sl + 8192 + tid * 16);
        gload_lds16(bSrc0 + off, sl + 16384 + tid * 16);
        gload_lds16(bSrc1 + off, sl + 24576 + tid * 16);
    }

    floatx16 acc[4][2];
    #pragma unroll
    for (int i = 0; i < 4; ++i)
        #pragma unroll
        for (int j = 0; j < 2; ++j)
            acc[i][j] = (floatx16)0.0f;

    int l16 = lane * 16;
    int s = 0;
    for (int t = 0; t < KT; ++t) {
        // wait own stage loads for tile t (keep tile t+1's 4 in flight),
        // then barrier => ALL waves' loads for tile t have landed.
        if (t == KT - 1) {
            asm volatile("s_waitcnt vmcnt(0)" ::: "memory");
        } else {
            asm volatile("s_waitcnt vmcnt(4)" ::: "memory");
        }
        __builtin_amdgcn_s_barrier();

        const uint8_t* slot = lds + s * 32768;
        const uint8_t* aB = slot + wm * 8192 + l16;                            // wave's A chunk
        const uint8_t* bB = slot + 16384 + (wn >> 1) * 8192 + (wn & 1) * 2048 + l16;

        // --- fragment reads (SSA concat; staircase order) ---
        intx8 fa0 = frag_ld(aB);
        intx8 fb0 = frag_ld(bB);
        intx8 fb1 = frag_ld(bB + 1024);
        intx8 fa1 = frag_ld(aB + 1024);

        // --- prefetch tile t+2 into the slot tile t-1 occupied ---
        int ns = s + 2; if (ns >= 3) ns -= 3;
        if (t + 2 < KT) {
            uint8_t* psl = lds + ns * 32768;
            size_t poff = (size_t)(t + 2) * 8192;
            gload_lds16(aSrc0 + poff, psl + tid * 16);
            gload_lds16(aSrc1 + poff, psl + 8192 + tid * 16);
            gload_lds16(bSrc0 + poff, psl + 16384 + tid * 16);
            gload_lds16(bSrc1 + poff, psl + 24576 + tid * 16);
        }

        // --- late reads (keep frag register peak low) ---
        intx8 fa2 = frag_ld(aB + 2048);
        intx8 fa3 = frag_ld(aB + 3072);

        // --- MFMA staircase: compiler emits counted lgkmcnt per dependency ---
        acc[0][0] = MFMA_SC(fa0, fb0, acc[0][0]);
        acc[0][1] = MFMA_SC(fa0, fb1, acc[0][1]);
        acc[1][0] = MFMA_SC(fa1, fb0, acc[1][0]);
        acc[1][1] = MFMA_SC(fa1, fb1, acc[1][1]);
        acc[2][0] = MFMA_SC(fa2, fb0, acc[2][0]);
        acc[2][1] = MFMA_SC(fa2, fb1, acc[2][1]);
        acc[3][0] = MFMA_SC(fa3, fb0, acc[3][0]);
        acc[3][1] = MFMA_SC(fa3, fb1, acc[3][1]);

        s = (s == 2) ? 0 : s + 1;
    }

    // epilogue: 32x32 C/D layout: col = lane&31, row = (reg&3) + 8*(reg>>2) + 4*(lane>>5)
    int cn = lane & 31;
    int h4 = (lane >> 5) * 4;
    long tileM = (long)by * 256;
    long tileN = (long)bx * 256;
    #pragma unroll
    for (int ni = 0; ni < 2; ++ni) {
        long col = tileN + wn * 64 + ni * 32 + cn;
        float bv = bias[col];
        #pragma unroll
        for (int mi = 0; mi < 4; ++mi) {
            long rowBase = tileM + wm * 128 + mi * 32 + h4;
            floatx16 a = acc[mi][ni];
            #pragma unroll
            for (int rg = 0; rg < 4; ++rg) {
                long row = rowBase + 8 * rg;
                #pragma unroll
                for (int rr = 0; rr < 4; ++rr)
                    C[(row + rr) * N_DIM + col] = a[rg * 4 + rr] * dq + bv;
            }
        }
    }
}

// ---------- launch ----------

extern "C" void kernel_launch(void* const* d_in, const int* in_sizes, int n_in,
                              void* d_out, int out_size, void* d_ws, size_t ws_size,
                              hipStream_t stream) {
    const float* x = (const float*)d_in[0];     // [M][K]
    const float* w = (const float*)d_in[1];     // [K][N]
    const float* bias = (const float*)d_in[2];  // [N]
    float* out = (float*)d_out;                 // [M][N]

    uint32_t* amax = (uint32_t*)d_ws;           // [0]=amax_x, [1]=amax_w
    uint8_t* qx = (uint8_t*)d_ws + 256;
    uint8_t* qwT = qx + (size_t)M_DIM * K_DIM;

    init_amax_kernel<<<1, 64, 0, stream>>>(amax);
    amax_kernel<<<3072, 256, 0, stream>>>(x, w, amax);
    quant_kernel<<<6144, 256, 0, stream>>>(x, w, qx, qwT, amax);
    gemm_kernel<<<dim3(N_DIM / 256, M_DIM / 256), 512, 0, stream>>>(qx, qwT, bias, out, amax);
}

// Round 4
// 396.746 us; speedup vs baseline: 1.1590x; 1.0483x over previous
//
#include <hip/hip_runtime.h>
#include <stdint.h>

#define M_DIM 8192
#define K_DIM 4096
#define N_DIM 4096
#define FP8_MAX 448.0f
#define KT (K_DIM / 64)   // 64 k-tiles of depth 64

typedef float floatx16 __attribute__((ext_vector_type(16)));
typedef int intx8 __attribute__((ext_vector_type(8)));
typedef int intx4 __attribute__((ext_vector_type(4)));

// Tiled fp8 layout (unchanged, proven):
//   tensor -> [128-row x 64-k] tiles of 8192 B; tile (i=row/128, b=k/64) at
//   (i*(K/64)+b)*8192. Within a tile: row = mi*32 + r5, k = h*32 + kq*16 + j
//     offset = kq*4096 + mi*1024 + (h*32 + r5)*16
//   MFMA 32x32x64 fragment read = TWO ds_read_b128 at
//   (kq*4096 + mi*1024) + 16*lane  (lane-contiguous, conflict-free).
//
// GEMM v6 (vs v5): cross-iteration register pipelining. v5 serialized the
// 96 KB/iter LDS drain (~1130 cy/CU) against the MFMA burst (~1100 cy/CU):
// measured 2334 cy/iter = their SUM. Now frags for tile t+1 are ds_read at
// the END of iter t (after vmcnt(4)+barrier), consumed at iter t+1 -> the
// LDS drain runs under the MFMA cluster via compiler counted-lgkm.
// Hazards: gloads for t+2 overwrite a slot whose reads were consumed two
// barriers earlier; frag reads of slot(t+1) follow own vmcnt + barrier
// (all waves' stage landed); sched_barrier(0) pins reads below the barrier.
//
// amax v2: no atomics. Per-block partial maxima -> d_out (gemm overwrites
// it entirely later); quant reduces 1536 partials per block and publishes
// scales to amax_bits. Kills the 3072 same-address atomicMax tail + one
// kernel launch (init).

// ---------- helpers ----------

__device__ __forceinline__ uint32_t pack4_fp8(float a, float b, float c, float d) {
    int v = __builtin_amdgcn_cvt_pk_fp8_f32(a, b, 0, false);
    v = __builtin_amdgcn_cvt_pk_fp8_f32(c, d, v, true);
    return (uint32_t)v;
}

__device__ __forceinline__ void gload_lds16(const uint8_t* g, uint8_t* l) {
    __builtin_amdgcn_global_load_lds(
        (const __attribute__((address_space(1))) uint32_t*)g,
        (__attribute__((address_space(3))) uint32_t*)l,
        16, 0, 0);
}

__device__ __forceinline__ float scale_from_amax(float amax) {
    return FP8_MAX / fmaxf(amax, 1e-12f);
}

// fragment load: two ds_read_b128 at +0 / +4096, SSA concat (no union, no movs)
__device__ __forceinline__ intx8 frag_ld(const uint8_t* p) {
    intx4 lo = *(const intx4*)p;
    intx4 hi = *(const intx4*)(p + 4096);
    return __builtin_shufflevector(lo, hi, 0, 1, 2, 3, 4, 5, 6, 7);
}

// ---------- kernel 1: per-tensor amax partials (no atomics) ----------
// blocks [0,1024): x ; [1024,1536): w.  partials -> d_out (overwritten by gemm)

__global__ __launch_bounds__(256)
void amax_kernel(const float* __restrict__ x, const float* __restrict__ w,
                 float* __restrict__ partials) {
    bool isX = blockIdx.x < 1024;
    const float4* s4 = (const float4*)(isX ? x : w);
    long n4 = (isX ? (long)M_DIM * K_DIM : (long)K_DIM * N_DIM) >> 2;
    int bid = isX ? blockIdx.x : blockIdx.x - 1024;
    int nb = isX ? 1024 : 512;
    long i = (long)bid * blockDim.x + threadIdx.x;
    long stride = (long)nb * blockDim.x;
    float m = 0.0f;
    for (long j = i; j < n4; j += stride) {
        float4 v = s4[j];
        m = fmaxf(m, fmaxf(fmaxf(fabsf(v.x), fabsf(v.y)), fmaxf(fabsf(v.z), fabsf(v.w))));
    }
    #pragma unroll
    for (int off = 32; off > 0; off >>= 1)
        m = fmaxf(m, __shfl_down(m, off, 64));
    __shared__ float smax[4];
    int wave = threadIdx.x >> 6;
    if ((threadIdx.x & 63) == 0) smax[wave] = m;
    __syncthreads();
    if (threadIdx.x == 0)
        partials[blockIdx.x] = fmaxf(fmaxf(smax[0], smax[1]), fmaxf(smax[2], smax[3]));
}

// ---------- kernel 2: fused quantize x and w -> tiled fp8 layouts ----------
// blocks [0,4096): x tiles; [4096,6144): wT tiles. Reduces partials first.

__global__ __launch_bounds__(256)
void quant_kernel(const float* __restrict__ x, const float* __restrict__ w,
                  uint8_t* __restrict__ qx, uint8_t* __restrict__ qwT,
                  const float* __restrict__ partials,
                  uint32_t* __restrict__ amax_bits) {
    int b = blockIdx.x;
    bool isX = b < 4096;

    // reduce per-block partials -> tensor amax (deterministic, identical in
    // every block of the same tensor)
    __shared__ float red[4];
    {
        const float* P = partials + (isX ? 0 : 1024);
        int cnt = isX ? 1024 : 512;
        float m = 0.0f;
        for (int i = threadIdx.x; i < cnt; i += 256) m = fmaxf(m, P[i]);
        #pragma unroll
        for (int off = 32; off > 0; off >>= 1)
            m = fmaxf(m, __shfl_down(m, off, 64));
        if ((threadIdx.x & 63) == 0) red[threadIdx.x >> 6] = m;
        __syncthreads();
    }
    float bm = fmaxf(fmaxf(red[0], red[1]), fmaxf(red[2], red[3]));
    float scale = scale_from_amax(bm);
    if (threadIdx.x == 0 && (b == 0 || b == 4096))
        amax_bits[isX ? 0 : 1] = __float_as_uint(bm);   // publish for gemm

    if (isX) {
        int iy = b >> 6, ib = b & 63;
        const float* src = x + (long)iy * 128 * K_DIM;
        uint8_t* outT = qx + (size_t)b * 8192;
        int kb = ib * 64;
        #pragma unroll
        for (int it = 0; it < 2; ++it) {
            int G = threadIdx.x + it * 256;
            int kq = G >> 8, rem = G & 255;
            int mi = rem >> 6, h = (rem >> 5) & 1, r5 = rem & 31;
            const float4* p = (const float4*)(src + (long)(mi * 32 + r5) * K_DIM
                                              + kb + h * 32 + kq * 16);
            float4 v0 = p[0], v1 = p[1], v2 = p[2], v3 = p[3];
            uint4 o;
            o.x = pack4_fp8(v0.x * scale, v0.y * scale, v0.z * scale, v0.w * scale);
            o.y = pack4_fp8(v1.x * scale, v1.y * scale, v1.z * scale, v1.w * scale);
            o.z = pack4_fp8(v2.x * scale, v2.y * scale, v2.z * scale, v2.w * scale);
            o.w = pack4_fp8(v3.x * scale, v3.y * scale, v3.z * scale, v3.w * scale);
            *(uint4*)(outT + (size_t)G * 16) = o;   // consecutive G -> coalesced
        }
    } else {
        b -= 4096;
        int iy = b >> 6, ib = b & 63;     // iy = n-tile
        int n0 = iy * 128, kb = ib * 64;
        uint8_t* outT = qwT + (size_t)b * 8192;
        #pragma unroll
        for (int it = 0; it < 2; ++it) {
            int G = threadIdx.x + it * 256;
            int kq = G >> 8, rem = G & 255;
            int mi = rem >> 6, h = (rem >> 5) & 1, r5 = rem & 31;
            int n = n0 + mi * 32 + r5;
            const float* col = w + (long)(kb + h * 32 + kq * 16) * N_DIM + n;
            float v[16];
            #pragma unroll
            for (int j = 0; j < 16; ++j)
                v[j] = col[(long)j * N_DIM] * scale;   // wave-coalesced per j
            uint4 o;
            o.x = pack4_fp8(v[0], v[1], v[2], v[3]);
            o.y = pack4_fp8(v[4], v[5], v[6], v[7]);
            o.z = pack4_fp8(v[8], v[9], v[10], v[11]);
            o.w = pack4_fp8(v[12], v[13], v[14], v[15]);
            *(uint4*)(outT + (size_t)G * 16) = o;
        }
    }
}

// ---------- kernel 3: MX-scaled fp8 MFMA GEMM, cross-iter reg pipeline ----------

#define UNIT_SCALE 0x7F7F7F7F   // e8m0 0x7F = 2^0 = 1.0 per 32-elem block

#define MFMA_SC(A, B, Cacc) \
    __builtin_amdgcn_mfma_scale_f32_32x32x64_f8f6f4( \
        (A), (B), (Cacc), 0, 0, 0, UNIT_SCALE, 0, UNIT_SCALE)

#define STAGE(PSL, OFF)                                     \
    gload_lds16(aSrc0 + (OFF), (PSL) + tid * 16);           \
    gload_lds16(aSrc1 + (OFF), (PSL) + 8192 + tid * 16);    \
    gload_lds16(bSrc0 + (OFF), (PSL) + 16384 + tid * 16);   \
    gload_lds16(bSrc1 + (OFF), (PSL) + 24576 + tid * 16);

// staircase order: reads feeding the first MFMAs first
#define READ_FRAGS(SLOT)                                                \
    {                                                                   \
        const uint8_t* aB_ = (SLOT) + wm * 8192 + l16;                  \
        const uint8_t* bB_ = (SLOT) + 16384 + (wn >> 1) * 8192          \
                             + (wn & 1) * 2048 + l16;                   \
        fa0 = frag_ld(aB_);                                             \
        fb0 = frag_ld(bB_);                                             \
        fb1 = frag_ld(bB_ + 1024);                                      \
        fa1 = frag_ld(aB_ + 1024);                                      \
        fa2 = frag_ld(aB_ + 2048);                                      \
        fa3 = frag_ld(aB_ + 3072);                                      \
    }

#define MFMA8()                                   \
    acc[0][0] = MFMA_SC(fa0, fb0, acc[0][0]);     \
    acc[0][1] = MFMA_SC(fa0, fb1, acc[0][1]);     \
    acc[1][0] = MFMA_SC(fa1, fb0, acc[1][0]);     \
    acc[1][1] = MFMA_SC(fa1, fb1, acc[1][1]);     \
    acc[2][0] = MFMA_SC(fa2, fb0, acc[2][0]);     \
    acc[2][1] = MFMA_SC(fa2, fb1, acc[2][1]);     \
    acc[3][0] = MFMA_SC(fa3, fb0, acc[3][0]);     \
    acc[3][1] = MFMA_SC(fa3, fb1, acc[3][1]);

__global__ __launch_bounds__(512, 2)
void gemm_kernel(const uint8_t* __restrict__ qx, const uint8_t* __restrict__ qwT,
                 const float* __restrict__ bias, float* __restrict__ C,
                 const uint32_t* __restrict__ amax_bits) {
    float sx = scale_from_amax(__uint_as_float(amax_bits[0]));
    float sw = scale_from_amax(__uint_as_float(amax_bits[1]));
    float dq = 1.0f / (sx * sw);

    // 3 slots x (A: 2x8KB chunks, B: 2x8KB chunks) = 96 KB
    __shared__ __align__(16) uint8_t lds[3 * 32768];

    int tid = threadIdx.x;
    int wave = tid >> 6;
    int lane = tid & 63;
    int wm = wave >> 2;        // 0..1 : 128 rows each
    int wn = wave & 3;         // 0..3 : 64 cols each

    // bijective XCD swizzle: 512 blocks -> 8 regions of 8N x 8M tiles
    int flat = blockIdx.y * gridDim.x + blockIdx.x;
    int xcd = flat & 7;
    int idx = flat >> 3;                  // 0..63 within region
    int bx = (xcd & 1) * 8 + (idx & 7);   // N-tile 0..15
    int by = (xcd >> 1) * 8 + (idx >> 3); // M-tile 0..31

    int i0 = by * 2;   // first 128-row A tile index
    int j0 = bx * 2;   // first 128-col B tile index

    const uint8_t* aSrc0 = qx  + ((size_t)(i0 + 0) * KT) * 8192 + tid * 16;
    const uint8_t* aSrc1 = qx  + ((size_t)(i0 + 1) * KT) * 8192 + tid * 16;
    const uint8_t* bSrc0 = qwT + ((size_t)(j0 + 0) * KT) * 8192 + tid * 16;
    const uint8_t* bSrc1 = qwT + ((size_t)(j0 + 1) * KT) * 8192 + tid * 16;

    floatx16 acc[4][2];
    #pragma unroll
    for (int i = 0; i < 4; ++i)
        #pragma unroll
        for (int j = 0; j < 2; ++j)
            acc[i][j] = (floatx16)0.0f;

    int l16 = lane * 16;

    // prologue: stage tile 0 -> slot0, tile 1 -> slot1; read tile-0 frags
    STAGE(lds, 0);
    STAGE(lds + 32768, 8192);
    asm volatile("s_waitcnt vmcnt(4)" ::: "memory");   // tile 0 landed
    __builtin_amdgcn_s_barrier();
    __builtin_amdgcn_sched_barrier(0);
    intx8 fa0, fa1, fa2, fa3, fb0, fb1;
    READ_FRAGS(lds);

    int s = 0;
    #pragma unroll 1
    for (int t = 0; t < KT - 2; ++t) {
        // stage tile t+2 into the slot tile t-1 occupied (reads consumed 2 barriers ago)
        int ns = s + 2; if (ns >= 3) ns -= 3;
        STAGE(lds + ns * 32768, (size_t)(t + 2) * 8192);
        // MFMAs on in-register frags of tile t (counted-lgkm staircase vs
        // the reads issued at the end of the previous iteration)
        MFMA8();
        // own t+1 stage landed (t+2's 4 stay in flight); all-waves via barrier
        asm volatile("s_waitcnt vmcnt(4)" ::: "memory");
        __builtin_amdgcn_s_barrier();
        __builtin_amdgcn_sched_barrier(0);
        s = (s == 2) ? 0 : s + 1;
        READ_FRAGS(lds + s * 32768);   // tile t+1; drains under next MFMA8
    }
    // t = KT-2: nothing left to stage
    MFMA8();
    asm volatile("s_waitcnt vmcnt(0)" ::: "memory");
    __builtin_amdgcn_s_barrier();
    __builtin_amdgcn_sched_barrier(0);
    s = (s == 2) ? 0 : s + 1;
    READ_FRAGS(lds + s * 32768);       // tile KT-1
    // t = KT-1
    MFMA8();

    // epilogue: 32x32 C/D layout: col = lane&31, row = (reg&3) + 8*(reg>>2) + 4*(lane>>5)
    int cn = lane & 31;
    int h4 = (lane >> 5) * 4;
    long tileM = (long)by * 256;
    long tileN = (long)bx * 256;
    #pragma unroll
    for (int ni = 0; ni < 2; ++ni) {
        long col = tileN + wn * 64 + ni * 32 + cn;
        float bv = bias[col];
        #pragma unroll
        for (int mi = 0; mi < 4; ++mi) {
            long rowBase = tileM + wm * 128 + mi * 32 + h4;
            floatx16 a = acc[mi][ni];
            #pragma unroll
            for (int rg = 0; rg < 4; ++rg) {
                long row = rowBase + 8 * rg;
                #pragma unroll
                for (int rr = 0; rr < 4; ++rr)
                    C[(row + rr) * N_DIM + col] = a[rg * 4 + rr] * dq + bv;
            }
        }
    }
}

// ---------- launch ----------

extern "C" void kernel_launch(void* const* d_in, const int* in_sizes, int n_in,
                              void* d_out, int out_size, void* d_ws, size_t ws_size,
                              hipStream_t stream) {
    const float* x = (const float*)d_in[0];     // [M][K]
    const float* w = (const float*)d_in[1];     // [K][N]
    const float* bias = (const float*)d_in[2];  // [N]
    float* out = (float*)d_out;                 // [M][N]

    uint32_t* amax = (uint32_t*)d_ws;           // [0]=amax_x, [1]=amax_w
    uint8_t* qx = (uint8_t*)d_ws + 256;
    uint8_t* qwT = qx + (size_t)M_DIM * K_DIM;

    // amax partials live in d_out (1536 floats) - gemm overwrites all of it
    float* partials = out;

    amax_kernel<<<1536, 256, 0, stream>>>(x, w, partials);
    quant_kernel<<<6144, 256, 0, stream>>>(x, w, qx, qwT, partials, amax);
    gemm_kernel<<<dim3(N_DIM / 256, M_DIM / 256), 512, 0, stream>>>(qx, qwT, bias, out, amax);
}